// Round 1
// baseline (731.713 us; speedup 1.0000x reference)
//
#include <hip/hip_runtime.h>
#include <math.h>

constexpr int Nn = 50000;
constexpr int Mm = 4000;
constexpr int Ee = 320000;
constexpr int KPB = Ee / Mm;           // 80 entries per hyperedge (he_e = i % M)
constexpr float BINV = 1.0f / (float)KPB;
constexpr float EPSf = 1e-5f;

__device__ __forceinline__ float lrelu_f(float x) { return x >= 0.f ? x : 0.2f * x; }

__device__ __forceinline__ float wave_sum(float v) {
#pragma unroll
    for (int o = 32; o >= 1; o >>= 1) v += __shfl_xor(v, o, 64);
    return v;
}
__device__ __forceinline__ float wave_max(float v) {
#pragma unroll
    for (int o = 32; o >= 1; o >>= 1) v = fmaxf(v, __shfl_xor(v, o, 64));
    return v;
}

// ---------------- GEMM: C[R,128] = op(A[R,128] @ B[128x128 slice of ldb]) ----------------
template <bool LRELU>
__global__ __launch_bounds__(256) void gemm128(const float* __restrict__ A,
                                               const float* __restrict__ B, int ldb,
                                               const float* __restrict__ bias, float scale,
                                               float* __restrict__ C, int R) {
    __shared__ float As[128][9];
    __shared__ float Bs[8][128];
    const int t = threadIdx.x;
    const int row0 = blockIdx.x * 128;
    const int ty = t >> 4, tx = t & 15;

    float acc[8][8];
#pragma unroll
    for (int i = 0; i < 8; i++)
#pragma unroll
        for (int j = 0; j < 8; j++) acc[i][j] = 0.f;

    for (int k0 = 0; k0 < 128; k0 += 8) {
        // load A tile 128x8
        {
            int r = t >> 1;
            int kc = (t & 1) * 4;
            float4 av = make_float4(0.f, 0.f, 0.f, 0.f);
            if (row0 + r < R) av = *(const float4*)(A + (size_t)(row0 + r) * 128 + k0 + kc);
            As[r][kc + 0] = av.x; As[r][kc + 1] = av.y; As[r][kc + 2] = av.z; As[r][kc + 3] = av.w;
        }
        // load B tile 8x128
        {
            int kk = t >> 5;
            int c = (t & 31) * 4;
            float4 bv = *(const float4*)(B + (size_t)(k0 + kk) * ldb + c);
            *(float4*)&Bs[kk][c] = bv;
        }
        __syncthreads();
#pragma unroll
        for (int kk = 0; kk < 8; kk++) {
            float a_[8], b_[8];
#pragma unroll
            for (int i = 0; i < 8; i++) a_[i] = As[ty * 8 + i][kk];
#pragma unroll
            for (int j = 0; j < 8; j++) b_[j] = Bs[kk][tx * 8 + j];
#pragma unroll
            for (int i = 0; i < 8; i++)
#pragma unroll
                for (int j = 0; j < 8; j++) acc[i][j] = fmaf(a_[i], b_[j], acc[i][j]);
        }
        __syncthreads();
    }

    float bvals[8];
#pragma unroll
    for (int j = 0; j < 8; j++) bvals[j] = bias ? bias[tx * 8 + j] : 0.f;
#pragma unroll
    for (int i = 0; i < 8; i++) {
        int row = row0 + ty * 8 + i;
        if (row >= R) continue;
        float vv[8];
#pragma unroll
        for (int j = 0; j < 8; j++) {
            float v = acc[i][j] * scale + bvals[j];
            if (LRELU) v = lrelu_f(v);
            vv[j] = v;
        }
        float4* cp = (float4*)(C + (size_t)row * 128 + tx * 8);
        cp[0] = make_float4(vv[0], vv[1], vv[2], vv[3]);
        cp[1] = make_float4(vv[4], vv[5], vv[6], vv[7]);
    }
}

// ---------------- CSR build ----------------
__global__ void count_edges(const int* __restrict__ he_n, int* __restrict__ counts) {
    for (int e = blockIdx.x * blockDim.x + threadIdx.x; e < Ee; e += gridDim.x * blockDim.x)
        atomicAdd(&counts[he_n[e]], 1);
}

__global__ __launch_bounds__(256) void scan_block_sum(const int* __restrict__ counts,
                                                      int* __restrict__ bsum) {
    __shared__ int sd[256];
    int b = blockIdx.x, t = threadIdx.x;
    int s = 0;
#pragma unroll
    for (int i = 0; i < 4; i++) {
        int n = b * 1024 + t * 4 + i;
        if (n < Nn) s += counts[n];
    }
    sd[t] = s;
    __syncthreads();
    for (int st = 128; st >= 1; st >>= 1) {
        if (t < st) sd[t] += sd[t + st];
        __syncthreads();
    }
    if (t == 0) bsum[b] = sd[0];
}

__global__ void scan_top(int* __restrict__ bsum, int nb, int* __restrict__ offs) {
    if (threadIdx.x == 0) {
        int run = 0;
        for (int i = 0; i < nb; i++) {
            int v = bsum[i];
            bsum[i] = run;
            run += v;
        }
        offs[Nn] = run;
    }
}

__global__ __launch_bounds__(256) void scan_write(const int* __restrict__ counts,
                                                  const int* __restrict__ bsum,
                                                  int* __restrict__ offs) {
    __shared__ int sd[256];
    int b = blockIdx.x, t = threadIdx.x;
    int c4[4];
    int s = 0;
#pragma unroll
    for (int i = 0; i < 4; i++) {
        int n = b * 1024 + t * 4 + i;
        c4[i] = (n < Nn) ? counts[n] : 0;
        s += c4[i];
    }
    sd[t] = s;
    __syncthreads();
    for (int off = 1; off < 256; off <<= 1) {
        int v = (t >= off) ? sd[t - off] : 0;
        __syncthreads();
        sd[t] += v;
        __syncthreads();
    }
    int run = sd[t] - s + bsum[b];
#pragma unroll
    for (int i = 0; i < 4; i++) {
        int n = b * 1024 + t * 4 + i;
        if (n < Nn) offs[n] = run;
        run += c4[i];
    }
}

__global__ void fill_csr(const int* __restrict__ he_n, const int* __restrict__ offs,
                         int* __restrict__ cursor, int* __restrict__ eid) {
    for (int e = blockIdx.x * blockDim.x + threadIdx.x; e < Ee; e += gridDim.x * blockDim.x) {
        int n = he_n[e];
        int p = atomicAdd(&cursor[n], 1);
        eid[offs[n] + p] = e;
    }
}

// ---------------- BN stats / finalize / apply ----------------
__global__ __launch_bounds__(256) void col_stats(const float* __restrict__ X,
                                                 double* __restrict__ st) {
    __shared__ double s1[256], s2[256];
    int tid = threadIdx.x;
    int c = tid & 127;
    double sum = 0, sq = 0;
    for (int r = blockIdx.x * 2 + (tid >> 7); r < Nn; r += gridDim.x * 2) {
        double v = X[(size_t)r * 128 + c];
        sum += v;
        sq += v * v;
    }
    s1[tid] = sum;
    s2[tid] = sq;
    __syncthreads();
    if (tid < 128) {
        atomicAdd(&st[c], s1[tid] + s1[tid + 128]);
        atomicAdd(&st[128 + c], s2[tid] + s2[tid + 128]);
    }
}

__global__ void bn_finalize(const double* __restrict__ st, const float* __restrict__ g,
                            const float* __restrict__ b, float* __restrict__ AB) {
    int c = threadIdx.x;
    double mean = st[c] / (double)Nn;
    double var = st[128 + c] / (double)Nn - mean * mean;
    float rstd = (float)(1.0 / sqrt(var + (double)EPSf));
    float A = g[c] * rstd;
    AB[c] = A;
    AB[128 + c] = b[c] - (float)mean * A;
}

// y = x*A + B per column; optionally compute an[row,h] = sum_k y[k]*wn[h*128+k]
template <int H>
__global__ __launch_bounds__(256) void bn_apply(const float* __restrict__ X,
                                                const float* __restrict__ AB,
                                                float* __restrict__ Y,
                                                const float* __restrict__ wn,
                                                float* __restrict__ an) {
    int w = threadIdx.x >> 6, lane = threadIdx.x & 63;
    int row = blockIdx.x * 4 + w;
    if (row >= Nn) return;
    const float* xr = X + (size_t)row * 128;
    float v0 = xr[lane] * AB[lane] + AB[128 + lane];
    float v1 = xr[lane + 64] * AB[lane + 64] + AB[128 + lane + 64];
    float* yr = Y + (size_t)row * 128;
    yr[lane] = v0;
    yr[lane + 64] = v1;
    if (H > 0) {
#pragma unroll
        for (int h = 0; h < H; h++) {
            float p = v0 * wn[h * 128 + lane] + v1 * wn[h * 128 + lane + 64];
            p = wave_sum(p);
            if (lane == 0) an[row * H + h] = p;
        }
    }
}

// ---------------- attention helpers ----------------
// wn[h][k] = sum_j W[k, h*128+j]*att[h, j];  we[h][k] = sum_j W[k, h*128+j]*att[h, 128+j]
template <int H>
__global__ void watt_kernel(const float* __restrict__ W, int ldw, const float* __restrict__ att,
                            float* __restrict__ wn, float* __restrict__ we) {
    int id = blockIdx.x * blockDim.x + threadIdx.x;
    if (id >= 128 * H * 2) return;
    int which = id / (128 * H);
    int rem = id % (128 * H);
    int h = rem >> 7, k = rem & 127;
    const float* a = att + h * 256 + which * 128;
    const float* w = W + (size_t)k * ldw + h * 128;
    float s = 0.f;
    for (int j = 0; j < 128; j++) s += w[j] * a[j];
    (which ? we : wn)[h * 128 + k] = s;
}

// ae[m,h] = (sum over 80 member rows of X) dot we[h]
template <int H>
__global__ __launch_bounds__(128) void ea_alpha(const float* __restrict__ X,
                                                const int* __restrict__ he_n,
                                                const float* __restrict__ we,
                                                float* __restrict__ ae) {
    __shared__ int idx[KPB];
    __shared__ float red[128];
    int m = blockIdx.x, tid = threadIdx.x;
    if (tid < KPB) idx[tid] = he_n[m + tid * Mm];
    __syncthreads();
    float acc = 0.f;
#pragma unroll 4
    for (int k = 0; k < KPB; k++) acc += X[(size_t)idx[k] * 128 + tid];
#pragma unroll
    for (int h = 0; h < H; h++) {
        red[tid] = acc * we[h * 128 + tid];
        __syncthreads();
        for (int s = 64; s >= 1; s >>= 1) {
            if (tid < s) red[tid] += red[tid + s];
            __syncthreads();
        }
        if (tid == 0) ae[m * H + h] = red[0];
        __syncthreads();
    }
}

// per-node softmax over incident edges; also Dinv
template <int H>
__global__ __launch_bounds__(256) void seg_softmax(const int* __restrict__ offs,
                                                   const int* __restrict__ eid,
                                                   const float* __restrict__ an,
                                                   const float* __restrict__ ae,
                                                   const float* __restrict__ he_w,
                                                   float* __restrict__ a_out,
                                                   float* __restrict__ Dinv) {
    int w = threadIdx.x >> 6, lane = threadIdx.x & 63;
    int n = blockIdx.x * 4 + w;
    if (n >= Nn) return;
    int base = offs[n];
    int deg = offs[n + 1] - base;
    float anv[H > 0 ? H : 1];
#pragma unroll
    for (int h = 0; h < H; h++) anv[h] = an[n * H + h];
    float mx[H > 0 ? H : 1];
#pragma unroll
    for (int h = 0; h < H; h++) mx[h] = -INFINITY;
    for (int c = lane; c < deg; c += 64) {
        int e = eid[base + c];
        int m = e % Mm;
#pragma unroll
        for (int h = 0; h < H; h++) mx[h] = fmaxf(mx[h], lrelu_f(anv[h] + ae[m * H + h]));
    }
#pragma unroll
    for (int h = 0; h < H; h++) mx[h] = wave_max(mx[h]);
    float sm[H > 0 ? H : 1];
#pragma unroll
    for (int h = 0; h < H; h++) sm[h] = 0.f;
    float dn = 0.f;
    for (int c = lane; c < deg; c += 64) {
        int e = eid[base + c];
        int m = e % Mm;
        dn += he_w[m];
#pragma unroll
        for (int h = 0; h < H; h++) sm[h] += expf(lrelu_f(anv[h] + ae[m * H + h]) - mx[h]);
    }
    dn = wave_sum(dn);
#pragma unroll
    for (int h = 0; h < H; h++) sm[h] = wave_sum(sm[h]);
    for (int c = lane; c < deg; c += 64) {
        int e = eid[base + c];
        int m = e % Mm;
#pragma unroll
        for (int h = 0; h < H; h++)
            a_out[e * H + h] = expf(lrelu_f(anv[h] + ae[m * H + h]) - mx[h]) / sm[h];
    }
    if (lane == 0) Dinv[n] = dn > 0.f ? 1.0f / dn : 0.0f;
}

// S[h][m][:] = sum_k a[e,h] * X[he_n[e], :]  for the 80 edges of hyperedge m
template <int H>
__global__ __launch_bounds__(128) void s_build(const float* __restrict__ X,
                                               const int* __restrict__ he_n,
                                               const float* __restrict__ a,
                                               float* __restrict__ S) {
    __shared__ int idx[KPB];
    __shared__ float av[KPB * H];
    int m = blockIdx.x, tid = threadIdx.x;
    if (tid < KPB) idx[tid] = he_n[m + tid * Mm];
    for (int q = tid; q < KPB * H; q += 128) {
        int k = q / H, h = q - k * H;
        av[q] = a[(size_t)(m + k * Mm) * H + h];
    }
    __syncthreads();
    float acc[H > 0 ? H : 1];
#pragma unroll
    for (int h = 0; h < H; h++) acc[h] = 0.f;
#pragma unroll 4
    for (int k = 0; k < KPB; k++) {
        float v = X[(size_t)idx[k] * 128 + tid];
#pragma unroll
        for (int h = 0; h < H; h++) acc[h] = fmaf(av[k * H + h], v, acc[h]);
    }
#pragma unroll
    for (int h = 0; h < H; h++) S[((size_t)h * Mm + m) * 128 + tid] = acc[h];
}

// out rows: T[n,:] = xres[n,:] + mean_h(Dinv[n]*sum_e a[e,h]*eo[h][m_e,:]) + bias
template <int H>
__global__ __launch_bounds__(256) void node_agg(const int* __restrict__ offs,
                                                const int* __restrict__ eid,
                                                const float* __restrict__ a,
                                                const float* __restrict__ eo,
                                                const float* __restrict__ Dinv,
                                                const float* __restrict__ bias,
                                                const float* __restrict__ xres,
                                                float* __restrict__ T) {
    int w = threadIdx.x >> 6, lane = threadIdx.x & 63;
    int n = blockIdx.x * 4 + w;
    if (n >= Nn) return;
    int base = offs[n];
    int deg = offs[n + 1] - base;
    float acc[2 * H];
#pragma unroll
    for (int r = 0; r < 2 * H; r++) acc[r] = 0.f;
    for (int i = 0; i < deg; i++) {
        int e = eid[base + i];
        int m = e % Mm;
        float av[H > 0 ? H : 1];
#pragma unroll
        for (int h = 0; h < H; h++) av[h] = a[e * H + h];
#pragma unroll
        for (int r = 0; r < 2 * H; r++) {
            int h = r >> 1;
            int j = (r & 1) * 64 + lane;
            acc[r] = fmaf(av[h], eo[((size_t)h * Mm + m) * 128 + j], acc[r]);
        }
    }
    float Dv = Dinv[n];
#pragma unroll
    for (int q = 0; q < 2; q++) {
        int j = q * 64 + lane;
        float x2 = (H == 2) ? 0.5f * Dv * (acc[q] + acc[q + 2]) : Dv * acc[q];
        x2 += bias[j];
        T[(size_t)n * 128 + j] = xres[(size_t)n * 128 + j] + x2;
    }
}

__global__ void add_vec(const float* __restrict__ a, const float* __restrict__ b,
                        float* __restrict__ o, int n4) {
    int i = blockIdx.x * blockDim.x + threadIdx.x;
    if (i < n4) {
        float4 x = ((const float4*)a)[i];
        float4 y = ((const float4*)b)[i];
        o[(size_t)i * 4 + 0] = x.x + y.x;
        o[(size_t)i * 4 + 1] = x.y + y.y;
        o[(size_t)i * 4 + 2] = x.z + y.z;
        o[(size_t)i * 4 + 3] = x.w + y.w;
    }
}

extern "C" void kernel_launch(void* const* d_in, const int* in_sizes, int n_in,
                              void* d_out, int out_size, void* d_ws, size_t ws_size,
                              hipStream_t stream) {
    const float* x = (const float*)d_in[0];
    const int* he_n = (const int*)d_in[1];
    const float* he_w = (const float*)d_in[3];
    const float* lin1_w = (const float*)d_in[4];
    const float* lin1_b = (const float*)d_in[5];
    const float* bn1_g = (const float*)d_in[6];
    const float* bn1_b = (const float*)d_in[7];
    const float* h1_w = (const float*)d_in[8];
    const float* h1_att = (const float*)d_in[9];
    const float* h1_b = (const float*)d_in[10];
    const float* bn2_g = (const float*)d_in[11];
    const float* bn2_b = (const float*)d_in[12];
    const float* h2_w = (const float*)d_in[13];
    const float* h2_att = (const float*)d_in[14];
    const float* h2_b = (const float*)d_in[15];
    const float* bn3_g = (const float*)d_in[16];
    const float* bn3_b = (const float*)d_in[17];
    const float* lin2_w = (const float*)d_in[18];
    const float* lin2_b = (const float*)d_in[19];
    const float* bn4_g = (const float*)d_in[20];
    const float* bn4_b = (const float*)d_in[21];
    float* out = (float*)d_out;

    char* ws = (char*)d_ws;
    size_t off = 0;
    auto alloc = [&](size_t bytes) -> char* {
        char* p = ws + off;
        off = (off + bytes + 255) & ~(size_t)255;
        return p;
    };
    // --- zeroed region (one memset) ---
    int* counts = (int*)alloc((size_t)Nn * 4);
    int* cursor = (int*)alloc((size_t)Nn * 4);
    double* stats = (double*)alloc(4 * 256 * 8);
    size_t zbytes = off;
    // --- rest ---
    int* offs = (int*)alloc((size_t)(Nn + 1) * 4);
    int* eid = (int*)alloc((size_t)Ee * 4);
    int* bsum = (int*)alloc(64 * 4);
    float* Dinv = (float*)alloc((size_t)Nn * 4);
    float* an = (float*)alloc((size_t)Nn * 2 * 4);
    float* ae = (float*)alloc((size_t)Mm * 2 * 4);
    float* aw = (float*)alloc((size_t)Ee * 2 * 4);
    float* S = (float*)alloc((size_t)2 * Mm * 128 * 4);
    float* eo = (float*)alloc((size_t)2 * Mm * 128 * 4);
    float* wn = (float*)alloc(2 * 128 * 4);
    float* we = (float*)alloc(2 * 128 * 4);
    float* AB = (float*)alloc(256 * 4);
    float* xb = (float*)alloc((size_t)Nn * 128 * 4);
    float* buf = (float*)alloc((size_t)Nn * 128 * 4);  // y and t share this buffer

    hipMemsetAsync(d_ws, 0, zbytes, stream);

    constexpr int NB = (Nn + 1023) / 1024;  // 49
    // CSR by node
    count_edges<<<1250, 256, 0, stream>>>(he_n, counts);
    scan_block_sum<<<NB, 256, 0, stream>>>(counts, bsum);
    scan_top<<<1, 64, 0, stream>>>(bsum, NB, offs);
    scan_write<<<NB, 256, 0, stream>>>(counts, bsum, offs);
    fill_csr<<<1250, 256, 0, stream>>>(he_n, offs, cursor, eid);

    // stage 1: y = lrelu(x@lin1_w + b); bn1 -> xb (+alpha_n for conv1)
    gemm128<true><<<(Nn + 127) / 128, 256, 0, stream>>>(x, lin1_w, 128, lin1_b, 1.f, buf, Nn);
    col_stats<<<256, 256, 0, stream>>>(buf, stats);
    bn_finalize<<<1, 128, 0, stream>>>(stats, bn1_g, bn1_b, AB);
    watt_kernel<2><<<1, 512, 0, stream>>>(h1_w, 256, h1_att, wn, we);
    bn_apply<2><<<12500, 256, 0, stream>>>(buf, AB, xb, wn, an);

    // hgconv1 (H=2)
    ea_alpha<2><<<Mm, 128, 0, stream>>>(xb, he_n, we, ae);
    seg_softmax<2><<<12500, 256, 0, stream>>>(offs, eid, an, ae, he_w, aw, Dinv);
    s_build<2><<<Mm, 128, 0, stream>>>(xb, he_n, aw, S);
    gemm128<false><<<(Mm + 127) / 128, 256, 0, stream>>>(S, h1_w, 256, nullptr, BINV, eo, Mm);
    gemm128<false><<<(Mm + 127) / 128, 256, 0, stream>>>(S + (size_t)Mm * 128, h1_w + 128, 256,
                                                         nullptr, BINV, eo + (size_t)Mm * 128, Mm);
    node_agg<2><<<12500, 256, 0, stream>>>(offs, eid, aw, eo, Dinv, h1_b, xb, buf);

    // bn2 -> xb (+alpha_n for conv2)
    col_stats<<<256, 256, 0, stream>>>(buf, stats + 256);
    bn_finalize<<<1, 128, 0, stream>>>(stats + 256, bn2_g, bn2_b, AB);
    watt_kernel<1><<<1, 256, 0, stream>>>(h2_w, 128, h2_att, wn, we);
    bn_apply<1><<<12500, 256, 0, stream>>>(buf, AB, xb, wn, an);

    // hgconv2 (H=1)
    ea_alpha<1><<<Mm, 128, 0, stream>>>(xb, he_n, we, ae);
    seg_softmax<1><<<12500, 256, 0, stream>>>(offs, eid, an, ae, he_w, aw, Dinv);
    s_build<1><<<Mm, 128, 0, stream>>>(xb, he_n, aw, S);
    gemm128<false><<<(Mm + 127) / 128, 256, 0, stream>>>(S, h2_w, 128, nullptr, BINV, eo, Mm);
    node_agg<1><<<12500, 256, 0, stream>>>(offs, eid, aw, eo, Dinv, h2_b, xb, buf);

    // bn3 -> xb
    col_stats<<<256, 256, 0, stream>>>(buf, stats + 512);
    bn_finalize<<<1, 128, 0, stream>>>(stats + 512, bn3_g, bn3_b, AB);
    bn_apply<0><<<12500, 256, 0, stream>>>(buf, AB, xb, nullptr, nullptr);

    // lin2 + residual + bn4 -> out
    gemm128<true><<<(Nn + 127) / 128, 256, 0, stream>>>(xb, lin2_w, 128, lin2_b, 1.f, buf, Nn);
    add_vec<<<(Nn * 128 / 4 + 255) / 256, 256, 0, stream>>>(x, buf, buf, Nn * 128 / 4);
    col_stats<<<256, 256, 0, stream>>>(buf, stats + 768);
    bn_finalize<<<1, 128, 0, stream>>>(stats + 768, bn4_g, bn4_b, AB);
    bn_apply<0><<<12500, 256, 0, stream>>>(buf, AB, out, nullptr, nullptr);
}

// Round 2
// 618.333 us; speedup vs baseline: 1.1834x; 1.1834x over previous
//
#include <hip/hip_runtime.h>
#include <math.h>

constexpr int Nn = 50000;
constexpr int Mm = 4000;
constexpr int Ee = 320000;
constexpr int KPB = Ee / Mm;           // 80 entries per hyperedge (he_e = i % M)
constexpr float BINV = 1.0f / (float)KPB;
constexpr float EPSf = 1e-5f;

__device__ __forceinline__ float lrelu_f(float x) { return x >= 0.f ? x : 0.2f * x; }

__device__ __forceinline__ float wave_sum(float v) {
#pragma unroll
    for (int o = 32; o >= 1; o >>= 1) v += __shfl_xor(v, o, 64);
    return v;
}
__device__ __forceinline__ float wave_max(float v) {
#pragma unroll
    for (int o = 32; o >= 1; o >>= 1) v = fmaxf(v, __shfl_xor(v, o, 64));
    return v;
}

// ---------------- GEMM: C[R,:] = op(op_bn(A[R,128]) @ B[128x128 slice of ldb]) ----------------
// PROBN: A[r][k] -> A[r][k]*ABin[k]+ABin[128+k] on load.
// LRELU: leaky relu after bias. RESID: += resid after lrelu. STATS: column sum/sumsq -> stats.
template <bool LRELU, bool PROBN, bool RESID, bool STATS>
__global__ __launch_bounds__(256) void gemm128(const float* __restrict__ A,
                                               const float* __restrict__ B, int ldb,
                                               const float* __restrict__ bias, float scale,
                                               const float* __restrict__ ABin,
                                               const float* __restrict__ resid,
                                               double* __restrict__ stats,
                                               float* __restrict__ C, int ldc, int R) {
    __shared__ float As[128][9];
    __shared__ float Bs[8][128];
    __shared__ float Sred[16][128];
    const int t = threadIdx.x;
    const int row0 = blockIdx.x * 128;
    const int ty = t >> 4, tx = t & 15;

    float acc[8][8];
#pragma unroll
    for (int i = 0; i < 8; i++)
#pragma unroll
        for (int j = 0; j < 8; j++) acc[i][j] = 0.f;

    for (int k0 = 0; k0 < 128; k0 += 8) {
        // load A tile 128x8
        {
            int r = t >> 1;
            int kc = (t & 1) * 4;
            float4 av = make_float4(0.f, 0.f, 0.f, 0.f);
            if (row0 + r < R) av = *(const float4*)(A + (size_t)(row0 + r) * 128 + k0 + kc);
            if (PROBN) {
                float4 sA = *(const float4*)(ABin + k0 + kc);
                float4 sB = *(const float4*)(ABin + 128 + k0 + kc);
                av.x = av.x * sA.x + sB.x; av.y = av.y * sA.y + sB.y;
                av.z = av.z * sA.z + sB.z; av.w = av.w * sA.w + sB.w;
            }
            As[r][kc + 0] = av.x; As[r][kc + 1] = av.y; As[r][kc + 2] = av.z; As[r][kc + 3] = av.w;
        }
        // load B tile 8x128
        {
            int kk = t >> 5;
            int c = (t & 31) * 4;
            float4 bv = *(const float4*)(B + (size_t)(k0 + kk) * ldb + c);
            *(float4*)&Bs[kk][c] = bv;
        }
        __syncthreads();
#pragma unroll
        for (int kk = 0; kk < 8; kk++) {
            float a_[8], b_[8];
#pragma unroll
            for (int i = 0; i < 8; i++) a_[i] = As[ty * 8 + i][kk];
#pragma unroll
            for (int j = 0; j < 8; j++) b_[j] = Bs[kk][tx * 8 + j];
#pragma unroll
            for (int i = 0; i < 8; i++)
#pragma unroll
                for (int j = 0; j < 8; j++) acc[i][j] = fmaf(a_[i], b_[j], acc[i][j]);
        }
        __syncthreads();
    }

    float bvals[8];
#pragma unroll
    for (int j = 0; j < 8; j++) bvals[j] = bias ? bias[tx * 8 + j] : 0.f;
    float csum[8], csq[8];
#pragma unroll
    for (int j = 0; j < 8; j++) { csum[j] = 0.f; csq[j] = 0.f; }
#pragma unroll
    for (int i = 0; i < 8; i++) {
        int row = row0 + ty * 8 + i;
        if (row >= R) continue;
        float vv[8];
#pragma unroll
        for (int j = 0; j < 8; j++) {
            float v = acc[i][j] * scale + bvals[j];
            if (LRELU) v = lrelu_f(v);
            if (RESID) v += resid[(size_t)row * 128 + tx * 8 + j];
            vv[j] = v;
            if (STATS) { csum[j] += v; csq[j] += v * v; }
        }
        float4* cp = (float4*)(C + (size_t)row * ldc + tx * 8);
        cp[0] = make_float4(vv[0], vv[1], vv[2], vv[3]);
        cp[1] = make_float4(vv[4], vv[5], vv[6], vv[7]);
    }
    if (STATS) {
        double* st = stats + (size_t)(blockIdx.x & 63) * 256;
#pragma unroll
        for (int pass = 0; pass < 2; pass++) {
#pragma unroll
            for (int j = 0; j < 8; j++) Sred[ty][tx * 8 + j] = pass ? csq[j] : csum[j];
            __syncthreads();
            if (t < 128) {
                float tot = 0.f;
#pragma unroll
                for (int r = 0; r < 16; r++) tot += Sred[r][t];
                atomicAdd(&st[pass * 128 + t], (double)tot);
            }
            __syncthreads();
        }
    }
}

// ---------------- CSR build ----------------
__global__ void count_edges(const int* __restrict__ he_n, int* __restrict__ counts) {
    for (int e = blockIdx.x * blockDim.x + threadIdx.x; e < Ee; e += gridDim.x * blockDim.x)
        atomicAdd(&counts[he_n[e]], 1);
}

__global__ __launch_bounds__(256) void scan_block_sum(const int* __restrict__ counts,
                                                      int* __restrict__ bsum) {
    __shared__ int sd[256];
    int b = blockIdx.x, t = threadIdx.x;
    int s = 0;
#pragma unroll
    for (int i = 0; i < 4; i++) {
        int n = b * 1024 + t * 4 + i;
        if (n < Nn) s += counts[n];
    }
    sd[t] = s;
    __syncthreads();
    for (int st = 128; st >= 1; st >>= 1) {
        if (t < st) sd[t] += sd[t + st];
        __syncthreads();
    }
    if (t == 0) bsum[b] = sd[0];
}

__global__ void scan_top(int* __restrict__ bsum, int nb, int* __restrict__ offs) {
    if (threadIdx.x == 0) {
        int run = 0;
        for (int i = 0; i < nb; i++) {
            int v = bsum[i];
            bsum[i] = run;
            run += v;
        }
        offs[Nn] = run;
    }
}

__global__ __launch_bounds__(256) void scan_write(const int* __restrict__ counts,
                                                  const int* __restrict__ bsum,
                                                  int* __restrict__ offs) {
    __shared__ int sd[256];
    int b = blockIdx.x, t = threadIdx.x;
    int c4[4];
    int s = 0;
#pragma unroll
    for (int i = 0; i < 4; i++) {
        int n = b * 1024 + t * 4 + i;
        c4[i] = (n < Nn) ? counts[n] : 0;
        s += c4[i];
    }
    sd[t] = s;
    __syncthreads();
    for (int off = 1; off < 256; off <<= 1) {
        int v = (t >= off) ? sd[t - off] : 0;
        __syncthreads();
        sd[t] += v;
        __syncthreads();
    }
    int run = sd[t] - s + bsum[b];
#pragma unroll
    for (int i = 0; i < 4; i++) {
        int n = b * 1024 + t * 4 + i;
        if (n < Nn) offs[n] = run;
        run += c4[i];
    }
}

__global__ void fill_csr(const int* __restrict__ he_n, const int* __restrict__ offs,
                         int* __restrict__ cursor, int* __restrict__ eid) {
    for (int e = blockIdx.x * blockDim.x + threadIdx.x; e < Ee; e += gridDim.x * blockDim.x) {
        int n = he_n[e];
        int p = atomicAdd(&cursor[n], 1);
        eid[offs[n] + p] = e;
    }
}

// ---------------- BN stats / finalize / apply ----------------
__global__ __launch_bounds__(256) void col_stats(const float* __restrict__ X,
                                                 double* __restrict__ st) {
    __shared__ double s1[256], s2[256];
    int tid = threadIdx.x;
    int c = tid & 127;
    double sum = 0, sq = 0;
    for (int r = blockIdx.x * 2 + (tid >> 7); r < Nn; r += gridDim.x * 2) {
        double v = X[(size_t)r * 128 + c];
        sum += v;
        sq += v * v;
    }
    s1[tid] = sum;
    s2[tid] = sq;
    __syncthreads();
    if (tid < 128) {
        double* stb = st + (size_t)(blockIdx.x & 63) * 256;
        atomicAdd(&stb[c], s1[tid] + s1[tid + 128]);
        atomicAdd(&stb[128 + c], s2[tid] + s2[tid + 128]);
    }
}

__global__ void bn_finalize(const double* __restrict__ st, const float* __restrict__ g,
                            const float* __restrict__ b, float* __restrict__ AB) {
    int c = threadIdx.x;
    double s = 0, sq = 0;
    for (int i = 0; i < 64; i++) {
        s += st[(size_t)i * 256 + c];
        sq += st[(size_t)i * 256 + 128 + c];
    }
    double mean = s / (double)Nn;
    double var = sq / (double)Nn - mean * mean;
    float rstd = (float)(1.0 / sqrt(var + (double)EPSf));
    float A = g[c] * rstd;
    AB[c] = A;
    AB[128 + c] = b[c] - (float)mean * A;
}

// y = x*A + B per column; an[row,h] = y . wn[h]; pe[row,h] = y . we[h]
template <int H>
__global__ __launch_bounds__(256) void bn_apply(const float* __restrict__ X,
                                                const float* __restrict__ AB,
                                                float* __restrict__ Y,
                                                const float* __restrict__ wn,
                                                const float* __restrict__ we,
                                                float* __restrict__ an,
                                                float* __restrict__ pe) {
    int w = threadIdx.x >> 6, lane = threadIdx.x & 63;
    int row = blockIdx.x * 4 + w;
    if (row >= Nn) return;
    const float* xr = X + (size_t)row * 128;
    float v0 = xr[lane] * AB[lane] + AB[128 + lane];
    float v1 = xr[lane + 64] * AB[lane + 64] + AB[128 + lane + 64];
    float* yr = Y + (size_t)row * 128;
    yr[lane] = v0;
    yr[lane + 64] = v1;
    if (H > 0) {
#pragma unroll
        for (int h = 0; h < H; h++) {
            float p = v0 * wn[h * 128 + lane] + v1 * wn[h * 128 + lane + 64];
            p = wave_sum(p);
            if (lane == 0) an[row * H + h] = p;
            float q = v0 * we[h * 128 + lane] + v1 * we[h * 128 + lane + 64];
            q = wave_sum(q);
            if (lane == 0) pe[row * H + h] = q;
        }
    }
}

// ---------------- attention helpers ----------------
template <int H>
__global__ void watt_kernel(const float* __restrict__ W, int ldw, const float* __restrict__ att,
                            float* __restrict__ wn, float* __restrict__ we) {
    int id = blockIdx.x * blockDim.x + threadIdx.x;
    if (id >= 128 * H * 2) return;
    int which = id / (128 * H);
    int rem = id % (128 * H);
    int h = rem >> 7, k = rem & 127;
    const float* a = att + h * 256 + which * 128;
    const float* w = W + (size_t)k * ldw + h * 128;
    float s = 0.f;
    for (int j = 0; j < 128; j++) s += w[j] * a[j];
    (which ? we : wn)[h * 128 + k] = s;
}

// ae[m,h] = sum over the 80 member nodes of pe[node,h]
template <int H>
__global__ __launch_bounds__(256) void ea_from_pe(const int* __restrict__ he_n,
                                                  const float* __restrict__ pe,
                                                  float* __restrict__ ae) {
    int w = threadIdx.x >> 6, lane = threadIdx.x & 63;
    int m = blockIdx.x * 4 + w;
    if (m >= Mm) return;
    float s[H > 0 ? H : 1];
#pragma unroll
    for (int h = 0; h < H; h++) s[h] = 0.f;
    for (int k = lane; k < KPB; k += 64) {
        int idx = he_n[m + k * Mm];
#pragma unroll
        for (int h = 0; h < H; h++) s[h] += pe[idx * H + h];
    }
#pragma unroll
    for (int h = 0; h < H; h++) s[h] = wave_sum(s[h]);
    if (lane == 0)
#pragma unroll
        for (int h = 0; h < H; h++) ae[m * H + h] = s[h];
}

// per-node softmax; writes edge-ordered aw (for s_build) and CSR-packed slot data sd
// sd slot (H=2): float4 {as_float(m), a0*Dinv/2, a1*Dinv/2, 0}; (H=1): float2 {as_float(m), a*Dinv}
template <int H>
__global__ __launch_bounds__(256) void seg_softmax(const int* __restrict__ offs,
                                                   const int* __restrict__ eid,
                                                   const float* __restrict__ an,
                                                   const float* __restrict__ ae,
                                                   const float* __restrict__ he_w,
                                                   float* __restrict__ aw,
                                                   float* __restrict__ sd) {
    int w = threadIdx.x >> 6, lane = threadIdx.x & 63;
    int n = blockIdx.x * 4 + w;
    if (n >= Nn) return;
    int base = offs[n];
    int deg = offs[n + 1] - base;
    float anv[H > 0 ? H : 1];
#pragma unroll
    for (int h = 0; h < H; h++) anv[h] = an[n * H + h];
    float mx[H > 0 ? H : 1];
#pragma unroll
    for (int h = 0; h < H; h++) mx[h] = -INFINITY;
    for (int c = lane; c < deg; c += 64) {
        int e = eid[base + c];
        int m = e % Mm;
#pragma unroll
        for (int h = 0; h < H; h++) mx[h] = fmaxf(mx[h], lrelu_f(anv[h] + ae[m * H + h]));
    }
#pragma unroll
    for (int h = 0; h < H; h++) mx[h] = wave_max(mx[h]);
    float sm[H > 0 ? H : 1];
#pragma unroll
    for (int h = 0; h < H; h++) sm[h] = 0.f;
    float dn = 0.f;
    for (int c = lane; c < deg; c += 64) {
        int e = eid[base + c];
        int m = e % Mm;
        dn += he_w[m];
#pragma unroll
        for (int h = 0; h < H; h++) sm[h] += expf(lrelu_f(anv[h] + ae[m * H + h]) - mx[h]);
    }
    dn = wave_sum(dn);
#pragma unroll
    for (int h = 0; h < H; h++) sm[h] = wave_sum(sm[h]);
    float Dv = dn > 0.f ? 1.0f / dn : 0.0f;
    float premul = Dv * (H == 2 ? 0.5f : 1.0f);
    for (int c = lane; c < deg; c += 64) {
        int e = eid[base + c];
        int m = e % Mm;
        float p[H > 0 ? H : 1];
#pragma unroll
        for (int h = 0; h < H; h++) {
            p[h] = expf(lrelu_f(anv[h] + ae[m * H + h]) - mx[h]) / sm[h];
            aw[e * H + h] = p[h];
        }
        if (H == 2) {
            *(float4*)(sd + (size_t)(base + c) * 4) =
                make_float4(__int_as_float(m), p[0] * premul, p[1] * premul, 0.f);
        } else {
            *(float2*)(sd + (size_t)(base + c) * 2) =
                make_float2(__int_as_float(m), p[0] * premul);
        }
    }
}

// S[h][m][:] = sum_k a[e,h] * X[he_n[e], :]
template <int H>
__global__ __launch_bounds__(128) void s_build(const float* __restrict__ X,
                                               const int* __restrict__ he_n,
                                               const float* __restrict__ a,
                                               float* __restrict__ S) {
    __shared__ int idx[KPB];
    __shared__ float av[KPB * H];
    int m = blockIdx.x, tid = threadIdx.x;
    if (tid < KPB) idx[tid] = he_n[m + tid * Mm];
    for (int q = tid; q < KPB * H; q += 128) {
        int k = q / H, h = q - k * H;
        av[q] = a[(size_t)(m + k * Mm) * H + h];
    }
    __syncthreads();
    float acc[H > 0 ? H : 1];
#pragma unroll
    for (int h = 0; h < H; h++) acc[h] = 0.f;
#pragma unroll 4
    for (int k = 0; k < KPB; k++) {
        float v = X[(size_t)idx[k] * 128 + tid];
#pragma unroll
        for (int h = 0; h < H; h++) acc[h] = fmaf(av[k * H + h], v, acc[h]);
    }
#pragma unroll
    for (int h = 0; h < H; h++) S[((size_t)h * Mm + m) * 128 + tid] = acc[h];
}

// T[n,:] = xres[n,:] + bias + sum_slots sum_h sd_a[slot,h] * eo[m_slot][h*128 + :]
template <int H>
__global__ __launch_bounds__(256) void node_agg(const int* __restrict__ offs,
                                                const float* __restrict__ sd,
                                                const float* __restrict__ eo,
                                                const float* __restrict__ bias,
                                                const float* __restrict__ xres,
                                                float* __restrict__ T) {
    int w = threadIdx.x >> 6, lane = threadIdx.x & 63;
    int n = blockIdx.x * 4 + w;
    if (n >= Nn) return;
    int base = offs[n];
    int deg = offs[n + 1] - base;
    float2 acc[H > 0 ? H : 1];
#pragma unroll
    for (int h = 0; h < H; h++) acc[h] = make_float2(0.f, 0.f);
    constexpr int SDW = (H == 2) ? 4 : 2;
    const float* sp = sd + (size_t)base * SDW;
    for (int c0 = 0; c0 < deg; c0 += 4) {
        int mi[4];
        float a0[4], a1[4];
#pragma unroll
        for (int j = 0; j < 4; j++) {
            int c = c0 + j;
            if (c < deg) {
                if (H == 2) {
                    float4 v = *(const float4*)(sp + (size_t)c * 4);
                    mi[j] = __float_as_int(v.x); a0[j] = v.y; a1[j] = v.z;
                } else {
                    float2 v = *(const float2*)(sp + (size_t)c * 2);
                    mi[j] = __float_as_int(v.x); a0[j] = v.y; a1[j] = 0.f;
                }
            } else {
                mi[j] = -1; a0[j] = 0.f; a1[j] = 0.f;
            }
        }
#pragma unroll
        for (int j = 0; j < 4; j++) {
            if (mi[j] < 0) continue;
            const float* er = eo + (size_t)mi[j] * (128 * H) + 2 * lane;
            float2 e0 = *(const float2*)er;
            acc[0].x = fmaf(a0[j], e0.x, acc[0].x);
            acc[0].y = fmaf(a0[j], e0.y, acc[0].y);
            if (H == 2) {
                float2 e1 = *(const float2*)(er + 128);
                acc[1].x = fmaf(a1[j], e1.x, acc[1].x);
                acc[1].y = fmaf(a1[j], e1.y, acc[1].y);
            }
        }
    }
    int col = 2 * lane;
    float2 xr = *(const float2*)(xres + (size_t)n * 128 + col);
    float r0 = xr.x + bias[col] + acc[0].x + (H == 2 ? acc[1].x : 0.f);
    float r1 = xr.y + bias[col + 1] + acc[0].y + (H == 2 ? acc[1].y : 0.f);
    *(float2*)(T + (size_t)n * 128 + col) = make_float2(r0, r1);
}

extern "C" void kernel_launch(void* const* d_in, const int* in_sizes, int n_in,
                              void* d_out, int out_size, void* d_ws, size_t ws_size,
                              hipStream_t stream) {
    const float* x = (const float*)d_in[0];
    const int* he_n = (const int*)d_in[1];
    const float* he_w = (const float*)d_in[3];
    const float* lin1_w = (const float*)d_in[4];
    const float* lin1_b = (const float*)d_in[5];
    const float* bn1_g = (const float*)d_in[6];
    const float* bn1_b = (const float*)d_in[7];
    const float* h1_w = (const float*)d_in[8];
    const float* h1_att = (const float*)d_in[9];
    const float* h1_b = (const float*)d_in[10];
    const float* bn2_g = (const float*)d_in[11];
    const float* bn2_b = (const float*)d_in[12];
    const float* h2_w = (const float*)d_in[13];
    const float* h2_att = (const float*)d_in[14];
    const float* h2_b = (const float*)d_in[15];
    const float* bn3_g = (const float*)d_in[16];
    const float* bn3_b = (const float*)d_in[17];
    const float* lin2_w = (const float*)d_in[18];
    const float* lin2_b = (const float*)d_in[19];
    const float* bn4_g = (const float*)d_in[20];
    const float* bn4_b = (const float*)d_in[21];
    float* out = (float*)d_out;

    char* ws = (char*)d_ws;
    size_t off = 0;
    auto alloc = [&](size_t bytes) -> char* {
        char* p = ws + off;
        off = (off + bytes + 255) & ~(size_t)255;
        return p;
    };
    // --- zeroed region (one memset) ---
    int* counts = (int*)alloc((size_t)Nn * 4);
    int* cursor = (int*)alloc((size_t)Nn * 4);
    double* stats = (double*)alloc((size_t)4 * 64 * 256 * 8);
    size_t zbytes = off;
    // --- rest ---
    int* offs = (int*)alloc((size_t)(Nn + 1) * 4);
    int* eid = (int*)alloc((size_t)Ee * 4);
    int* bsum = (int*)alloc(64 * 4);
    float* an = (float*)alloc((size_t)Nn * 2 * 4);
    float* pe = (float*)alloc((size_t)Nn * 2 * 4);
    float* ae = (float*)alloc((size_t)Mm * 2 * 4);
    float* aw = (float*)alloc((size_t)Ee * 2 * 4);
    float* sd = (float*)alloc((size_t)Ee * 4 * 4);
    float* S = (float*)alloc((size_t)2 * Mm * 128 * 4);
    float* eo = (float*)alloc((size_t)2 * Mm * 128 * 4);
    float* wn = (float*)alloc(2 * 128 * 4);
    float* we = (float*)alloc(2 * 128 * 4);
    float* AB = (float*)alloc(4 * 256 * 4);
    float* xb = (float*)alloc((size_t)Nn * 128 * 4);
    float* buf = (float*)alloc((size_t)Nn * 128 * 4);

    double* st0 = stats;
    double* st1 = stats + 64 * 256;
    double* st2 = stats + 2 * 64 * 256;
    double* st3 = stats + 3 * 64 * 256;
    float* AB1 = AB, *AB2 = AB + 256, *AB3 = AB + 512, *AB4 = AB + 768;

    hipMemsetAsync(d_ws, 0, zbytes, stream);

    constexpr int NB = (Nn + 1023) / 1024;  // 49
    // CSR by node
    count_edges<<<1250, 256, 0, stream>>>(he_n, counts);
    scan_block_sum<<<NB, 256, 0, stream>>>(counts, bsum);
    scan_top<<<1, 64, 0, stream>>>(bsum, NB, offs);
    scan_write<<<NB, 256, 0, stream>>>(counts, bsum, offs);
    fill_csr<<<1250, 256, 0, stream>>>(he_n, offs, cursor, eid);

    // stage 1: y = lrelu(x@lin1_w + b) with fused stats; bn1 apply -> xb (+an,pe)
    gemm128<true, false, false, true><<<(Nn + 127) / 128, 256, 0, stream>>>(
        x, lin1_w, 128, lin1_b, 1.f, nullptr, nullptr, st0, buf, 128, Nn);
    bn_finalize<<<1, 128, 0, stream>>>(st0, bn1_g, bn1_b, AB1);
    watt_kernel<2><<<1, 512, 0, stream>>>(h1_w, 256, h1_att, wn, we);
    bn_apply<2><<<12500, 256, 0, stream>>>(buf, AB1, xb, wn, we, an, pe);

    // hgconv1 (H=2)
    ea_from_pe<2><<<Mm / 4, 256, 0, stream>>>(he_n, pe, ae);
    seg_softmax<2><<<12500, 256, 0, stream>>>(offs, eid, an, ae, he_w, aw, sd);
    s_build<2><<<Mm, 128, 0, stream>>>(xb, he_n, aw, S);
    gemm128<false, false, false, false><<<(Mm + 127) / 128, 256, 0, stream>>>(
        S, h1_w, 256, nullptr, BINV, nullptr, nullptr, nullptr, eo, 256, Mm);
    gemm128<false, false, false, false><<<(Mm + 127) / 128, 256, 0, stream>>>(
        S + (size_t)Mm * 128, h1_w + 128, 256, nullptr, BINV, nullptr, nullptr, nullptr,
        eo + 128, 256, Mm);
    node_agg<2><<<12500, 256, 0, stream>>>(offs, sd, eo, h1_b, xb, buf);

    // bn2
    col_stats<<<256, 256, 0, stream>>>(buf, st1);
    bn_finalize<<<1, 128, 0, stream>>>(st1, bn2_g, bn2_b, AB2);
    watt_kernel<1><<<1, 256, 0, stream>>>(h2_w, 128, h2_att, wn, we);
    bn_apply<1><<<12500, 256, 0, stream>>>(buf, AB2, xb, wn, we, an, pe);

    // hgconv2 (H=1)
    ea_from_pe<1><<<Mm / 4, 256, 0, stream>>>(he_n, pe, ae);
    seg_softmax<1><<<12500, 256, 0, stream>>>(offs, eid, an, ae, he_w, aw, sd);
    s_build<1><<<Mm, 128, 0, stream>>>(xb, he_n, aw, S);
    gemm128<false, false, false, false><<<(Mm + 127) / 128, 256, 0, stream>>>(
        S, h2_w, 128, nullptr, BINV, nullptr, nullptr, nullptr, eo, 128, Mm);
    node_agg<1><<<12500, 256, 0, stream>>>(offs, sd, eo, h2_b, xb, buf);

    // bn3 stats; bn3-apply fused into lin2 GEMM prologue; lrelu+residual+stats4 in epilogue
    col_stats<<<256, 256, 0, stream>>>(buf, st2);
    bn_finalize<<<1, 128, 0, stream>>>(st2, bn3_g, bn3_b, AB3);
    gemm128<true, true, true, true><<<(Nn + 127) / 128, 256, 0, stream>>>(
        buf, lin2_w, 128, lin2_b, 1.f, AB3, x, st3, buf, 128, Nn);
    bn_finalize<<<1, 128, 0, stream>>>(st3, bn4_g, bn4_b, AB4);
    bn_apply<0><<<12500, 256, 0, stream>>>(buf, AB4, out, nullptr, nullptr, nullptr, nullptr);
}

// Round 3
// 562.351 us; speedup vs baseline: 1.3012x; 1.0995x over previous
//
#include <hip/hip_runtime.h>
#include <math.h>

constexpr int Nn = 50000;
constexpr int Mm = 4000;
constexpr int Ee = 320000;
constexpr int KPB = Ee / Mm;           // 80 entries per hyperedge (he_e = i % M)
constexpr float BINV = 1.0f / (float)KPB;
constexpr float EPSf = 1e-5f;

__device__ __forceinline__ float lrelu_f(float x) { return x >= 0.f ? x : 0.2f * x; }

__device__ __forceinline__ float wave_sum(float v) {
#pragma unroll
    for (int o = 32; o >= 1; o >>= 1) v += __shfl_xor(v, o, 64);
    return v;
}

// ---------------- GEMM: C[R, bcol:bcol+128] = op(op_bn(A[R,128]) @ B[:, bcol:bcol+128]) -----
// Per-thread tile: RPT rows x 8 interleaved cols (col = tx + 16*j) -> conflict-free LDS reads.
template <int ROWS, bool LRELU, bool PROBN, bool RESID, bool STATS>
__global__ __launch_bounds__(256) void gemmT(const float* __restrict__ A, size_t aystride,
                                             const float* __restrict__ B, int ldb,
                                             const float* __restrict__ bias, float scale,
                                             const float* __restrict__ ABin,
                                             const float* __restrict__ resid,
                                             double* __restrict__ stats,
                                             float* __restrict__ C, int ldc, int R) {
    constexpr int RPT = ROWS / 16;
    __shared__ float As[ROWS][9];
    __shared__ float Bs[8][128];
    __shared__ float Sred[STATS ? 16 : 1][128];
    const int t = threadIdx.x;
    const int row0 = blockIdx.x * ROWS;
    const int bcol = blockIdx.y * 128;
    A += (size_t)blockIdx.y * aystride;
    const int ty = t >> 4, tx = t & 15;

    float acc[RPT][8];
#pragma unroll
    for (int i = 0; i < RPT; i++)
#pragma unroll
        for (int j = 0; j < 8; j++) acc[i][j] = 0.f;

    for (int k0 = 0; k0 < 128; k0 += 8) {
        if (ROWS == 64) {
            int r = t >> 2, kc = (t & 3) * 2;
            float2 av = make_float2(0.f, 0.f);
            if (row0 + r < R) av = *(const float2*)(A + (size_t)(row0 + r) * 128 + k0 + kc);
            if (PROBN) {
                av.x = av.x * ABin[k0 + kc] + ABin[128 + k0 + kc];
                av.y = av.y * ABin[k0 + kc + 1] + ABin[128 + k0 + kc + 1];
            }
            As[r][kc] = av.x;
            As[r][kc + 1] = av.y;
        } else {  // ROWS == 32
            int r = t >> 3, kc = t & 7;
            float av = 0.f;
            if (row0 + r < R) av = A[(size_t)(row0 + r) * 128 + k0 + kc];
            if (PROBN) av = av * ABin[k0 + kc] + ABin[128 + k0 + kc];
            As[r][kc] = av;
        }
        {
            int kk = t >> 5, c = (t & 31) * 4;
            float4 bv = *(const float4*)(B + (size_t)(k0 + kk) * ldb + bcol + c);
            *(float4*)&Bs[kk][c] = bv;
        }
        __syncthreads();
#pragma unroll
        for (int kk = 0; kk < 8; kk++) {
            float a_[RPT], b_[8];
#pragma unroll
            for (int i = 0; i < RPT; i++) a_[i] = As[ty * RPT + i][kk];
#pragma unroll
            for (int j = 0; j < 8; j++) b_[j] = Bs[kk][tx + 16 * j];
#pragma unroll
            for (int i = 0; i < RPT; i++)
#pragma unroll
                for (int j = 0; j < 8; j++) acc[i][j] = fmaf(a_[i], b_[j], acc[i][j]);
        }
        __syncthreads();
    }

    float bvals[8];
#pragma unroll
    for (int j = 0; j < 8; j++) bvals[j] = bias ? bias[bcol + tx + 16 * j] : 0.f;
    float csum[8], csq[8];
#pragma unroll
    for (int j = 0; j < 8; j++) { csum[j] = 0.f; csq[j] = 0.f; }
#pragma unroll
    for (int i = 0; i < RPT; i++) {
        int row = row0 + ty * RPT + i;
        if (row >= R) continue;
#pragma unroll
        for (int j = 0; j < 8; j++) {
            float v = acc[i][j] * scale + bvals[j];
            if (LRELU) v = lrelu_f(v);
            if (RESID) v += resid[(size_t)row * 128 + bcol + tx + 16 * j];
            C[(size_t)row * ldc + bcol + tx + 16 * j] = v;
            if (STATS) { csum[j] += v; csq[j] += v * v; }
        }
    }
    if (STATS) {
        double* st = stats + (size_t)(blockIdx.x & 63) * 256;
#pragma unroll
        for (int pass = 0; pass < 2; pass++) {
#pragma unroll
            for (int j = 0; j < 8; j++) Sred[ty][tx + 16 * j] = pass ? csq[j] : csum[j];
            __syncthreads();
            if (t < 128) {
                float tot = 0.f;
#pragma unroll
                for (int r = 0; r < 16; r++) tot += Sred[r][t];
                atomicAdd(&st[pass * 128 + t], (double)tot);
            }
            __syncthreads();
        }
    }
}

// ---------------- CSR build ----------------
__global__ void count_edges(const int* __restrict__ he_n, int* __restrict__ counts) {
    for (int e = blockIdx.x * blockDim.x + threadIdx.x; e < Ee; e += gridDim.x * blockDim.x)
        atomicAdd(&counts[he_n[e]], 1);
}

__global__ __launch_bounds__(256) void scan_block_sum(const int* __restrict__ counts,
                                                      int* __restrict__ bsum) {
    __shared__ int sd[256];
    int b = blockIdx.x, t = threadIdx.x;
    int s = 0;
#pragma unroll
    for (int i = 0; i < 4; i++) {
        int n = b * 1024 + t * 4 + i;
        if (n < Nn) s += counts[n];
    }
    sd[t] = s;
    __syncthreads();
    for (int st = 128; st >= 1; st >>= 1) {
        if (t < st) sd[t] += sd[t + st];
        __syncthreads();
    }
    if (t == 0) bsum[b] = sd[0];
}

__global__ void scan_top(int* __restrict__ bsum, int nb, int* __restrict__ offs) {
    if (threadIdx.x == 0) {
        int run = 0;
        for (int i = 0; i < nb; i++) {
            int v = bsum[i];
            bsum[i] = run;
            run += v;
        }
        offs[Nn] = run;
    }
}

__global__ __launch_bounds__(256) void scan_write(const int* __restrict__ counts,
                                                  const int* __restrict__ bsum,
                                                  int* __restrict__ offs) {
    __shared__ int sd[256];
    int b = blockIdx.x, t = threadIdx.x;
    int c4[4];
    int s = 0;
#pragma unroll
    for (int i = 0; i < 4; i++) {
        int n = b * 1024 + t * 4 + i;
        c4[i] = (n < Nn) ? counts[n] : 0;
        s += c4[i];
    }
    sd[t] = s;
    __syncthreads();
    for (int off = 1; off < 256; off <<= 1) {
        int v = (t >= off) ? sd[t - off] : 0;
        __syncthreads();
        sd[t] += v;
        __syncthreads();
    }
    int run = sd[t] - s + bsum[b];
#pragma unroll
    for (int i = 0; i < 4; i++) {
        int n = b * 1024 + t * 4 + i;
        if (n < Nn) offs[n] = run;
        run += c4[i];
    }
}

__global__ void fill_csr(const int* __restrict__ he_n, const int* __restrict__ offs,
                         int* __restrict__ cursor, int* __restrict__ eid) {
    for (int e = blockIdx.x * blockDim.x + threadIdx.x; e < Ee; e += gridDim.x * blockDim.x) {
        int n = he_n[e];
        int p = atomicAdd(&cursor[n], 1);
        eid[offs[n] + p] = e;
    }
}

// ---------------- BN stats / finalize ----------------
__global__ __launch_bounds__(256) void col_stats(const float* __restrict__ X,
                                                 double* __restrict__ st) {
    __shared__ double s1[256], s2[256];
    int tid = threadIdx.x;
    int c = tid & 127;
    double sum = 0, sq = 0;
    for (int r = blockIdx.x * 2 + (tid >> 7); r < Nn; r += gridDim.x * 2) {
        double v = X[(size_t)r * 128 + c];
        sum += v;
        sq += v * v;
    }
    s1[tid] = sum;
    s2[tid] = sq;
    __syncthreads();
    if (tid < 128) {
        double* stb = st + (size_t)(blockIdx.x & 63) * 256;
        atomicAdd(&stb[c], s1[tid] + s1[tid + 128]);
        atomicAdd(&stb[128 + c], s2[tid] + s2[tid + 128]);
    }
}

__global__ void bn_finalize(const double* __restrict__ st, const float* __restrict__ g,
                            const float* __restrict__ b, float* __restrict__ AB) {
    int c = threadIdx.x;
    double s = 0, sq = 0;
    for (int i = 0; i < 64; i++) {
        s += st[(size_t)i * 256 + c];
        sq += st[(size_t)i * 256 + 128 + c];
    }
    double mean = s / (double)Nn;
    double var = sq / (double)Nn - mean * mean;
    float rstd = (float)(1.0 / sqrt(var + (double)EPSf));
    float A = g[c] * rstd;
    AB[c] = A;
    AB[128 + c] = b[c] - (float)mean * A;
}

// dots only: an[row,h] = BN(x_row) . wn[h]; pe[row,h] = BN(x_row) . we[h]  (no Y write)
template <int H>
__global__ __launch_bounds__(256) void bn_dots(const float* __restrict__ X,
                                               const float* __restrict__ AB,
                                               const float* __restrict__ wn,
                                               const float* __restrict__ we,
                                               float* __restrict__ an,
                                               float* __restrict__ pe) {
    int w = threadIdx.x >> 6, lane = threadIdx.x & 63;
    int row = blockIdx.x * 4 + w;
    if (row >= Nn) return;
    const float* xr = X + (size_t)row * 128;
    float v0 = xr[lane] * AB[lane] + AB[128 + lane];
    float v1 = xr[lane + 64] * AB[lane + 64] + AB[128 + lane + 64];
#pragma unroll
    for (int h = 0; h < H; h++) {
        float p = v0 * wn[h * 128 + lane] + v1 * wn[h * 128 + lane + 64];
        p = wave_sum(p);
        if (lane == 0) an[row * H + h] = p;
        float q = v0 * we[h * 128 + lane] + v1 * we[h * 128 + lane + 64];
        q = wave_sum(q);
        if (lane == 0) pe[row * H + h] = q;
    }
}

// final elementwise BN apply
__global__ __launch_bounds__(256) void bn_out(const float* __restrict__ X,
                                              const float* __restrict__ AB,
                                              float* __restrict__ Y) {
    int w = threadIdx.x >> 6, lane = threadIdx.x & 63;
    int row = blockIdx.x * 4 + w;
    if (row >= Nn) return;
    const float* xr = X + (size_t)row * 128;
    float* yr = Y + (size_t)row * 128;
    yr[lane] = xr[lane] * AB[lane] + AB[128 + lane];
    yr[lane + 64] = xr[lane + 64] * AB[lane + 64] + AB[128 + lane + 64];
}

// ---------------- attention helpers ----------------
template <int H>
__global__ void watt_kernel(const float* __restrict__ W, int ldw, const float* __restrict__ att,
                            float* __restrict__ wn, float* __restrict__ we) {
    int id = blockIdx.x * blockDim.x + threadIdx.x;
    if (id >= 128 * H * 2) return;
    int which = id / (128 * H);
    int rem = id % (128 * H);
    int h = rem >> 7, k = rem & 127;
    const float* a = att + h * 256 + which * 128;
    const float* w = W + (size_t)k * ldw + h * 128;
    float s = 0.f;
    for (int j = 0; j < 128; j++) s += w[j] * a[j];
    (which ? we : wn)[h * 128 + k] = s;
}

// ae[m,h] = sum over the 80 member nodes of pe[node,h]
template <int H>
__global__ __launch_bounds__(256) void ea_from_pe(const int* __restrict__ he_n,
                                                  const float* __restrict__ pe,
                                                  float* __restrict__ ae) {
    int w = threadIdx.x >> 6, lane = threadIdx.x & 63;
    int m = blockIdx.x * 4 + w;
    if (m >= Mm) return;
    float s[H];
#pragma unroll
    for (int h = 0; h < H; h++) s[h] = 0.f;
    for (int k = lane; k < KPB; k += 64) {
        int idx = he_n[m + k * Mm];
#pragma unroll
        for (int h = 0; h < H; h++) s[h] += pe[idx * H + h];
    }
#pragma unroll
    for (int h = 0; h < H; h++) s[h] = wave_sum(s[h]);
    if (lane == 0)
#pragma unroll
        for (int h = 0; h < H; h++) ae[m * H + h] = s[h];
}

// per-node softmax; 8 nodes per wave (8 lanes each). Writes edge-ordered aw and CSR slots sd.
template <int H>
__global__ __launch_bounds__(256) void seg_softmax(const int* __restrict__ offs,
                                                   const int* __restrict__ eid,
                                                   const float* __restrict__ an,
                                                   const float* __restrict__ ae,
                                                   const float* __restrict__ he_w,
                                                   float* __restrict__ aw,
                                                   float* __restrict__ sd) {
    int t = threadIdx.x;
    int wv = t >> 6, lane = t & 63;
    int q = lane >> 3, li = lane & 7;
    int n = blockIdx.x * 32 + wv * 8 + q;
    bool valid = n < Nn;
    int base = valid ? offs[n] : 0;
    int deg = valid ? offs[n + 1] - base : 0;
    float anv[H];
#pragma unroll
    for (int h = 0; h < H; h++) anv[h] = valid ? an[n * H + h] : 0.f;
    float mx[H];
#pragma unroll
    for (int h = 0; h < H; h++) mx[h] = -INFINITY;
    for (int c = li; c < deg; c += 8) {
        int e = eid[base + c];
        int m = e % Mm;
#pragma unroll
        for (int h = 0; h < H; h++) mx[h] = fmaxf(mx[h], lrelu_f(anv[h] + ae[m * H + h]));
    }
#pragma unroll
    for (int h = 0; h < H; h++) {
#pragma unroll
        for (int o = 1; o <= 4; o <<= 1) mx[h] = fmaxf(mx[h], __shfl_xor(mx[h], o, 64));
    }
    float sm[H];
#pragma unroll
    for (int h = 0; h < H; h++) sm[h] = 0.f;
    float dn = 0.f;
    for (int c = li; c < deg; c += 8) {
        int e = eid[base + c];
        int m = e % Mm;
        dn += he_w[m];
#pragma unroll
        for (int h = 0; h < H; h++) sm[h] += expf(lrelu_f(anv[h] + ae[m * H + h]) - mx[h]);
    }
#pragma unroll
    for (int o = 1; o <= 4; o <<= 1) dn += __shfl_xor(dn, o, 64);
#pragma unroll
    for (int h = 0; h < H; h++) {
#pragma unroll
        for (int o = 1; o <= 4; o <<= 1) sm[h] += __shfl_xor(sm[h], o, 64);
    }
    float Dv = dn > 0.f ? 1.0f / dn : 0.0f;
    float premul = Dv * (H == 2 ? 0.5f : 1.0f);
    for (int c = li; c < deg; c += 8) {
        int e = eid[base + c];
        int m = e % Mm;
        float p[H];
#pragma unroll
        for (int h = 0; h < H; h++) p[h] = expf(lrelu_f(anv[h] + ae[m * H + h]) - mx[h]) / sm[h];
        if (H == 2) {
            *(float2*)(aw + (size_t)e * 2) = make_float2(p[0], p[1]);
            *(float4*)(sd + (size_t)(base + c) * 4) =
                make_float4(__int_as_float(m), p[0] * premul, p[1] * premul, 0.f);
        } else {
            aw[e] = p[0];
            *(float2*)(sd + (size_t)(base + c) * 2) =
                make_float2(__int_as_float(m), p[0] * premul);
        }
    }
}

// S[h][m][:] = sum_k aw[e,h] * BN(X[he_n[e], :])   (vectorized: 8 groups x 32 lanes x float4)
template <int H>
__global__ __launch_bounds__(256) void s_build(const float* __restrict__ X,
                                               const float* __restrict__ AB,
                                               const int* __restrict__ he_n,
                                               const float* __restrict__ aw,
                                               float* __restrict__ S) {
    __shared__ int idx[KPB];
    __shared__ float av[KPB][H];
    __shared__ float red[8][H][128];
    int m = blockIdx.x, t = threadIdx.x;
    int g = t >> 5, l = t & 31;
    if (t < KPB) idx[t] = he_n[m + t * Mm];
    for (int q2 = t; q2 < KPB * H; q2 += 256) {
        int k = q2 / H, h = q2 - k * H;
        av[k][h] = aw[(size_t)(m + k * Mm) * H + h];
    }
    __syncthreads();
    float4 A4 = ((const float4*)AB)[l];
    float4 B4 = ((const float4*)(AB + 128))[l];
    float4 acc[H];
#pragma unroll
    for (int h = 0; h < H; h++) acc[h] = make_float4(0.f, 0.f, 0.f, 0.f);
#pragma unroll
    for (int kk = 0; kk < KPB / 8; kk++) {
        int k = g + kk * 8;
        float4 v = ((const float4*)(X + (size_t)idx[k] * 128))[l];
        v.x = v.x * A4.x + B4.x;
        v.y = v.y * A4.y + B4.y;
        v.z = v.z * A4.z + B4.z;
        v.w = v.w * A4.w + B4.w;
#pragma unroll
        for (int h = 0; h < H; h++) {
            float a = av[k][h];
            acc[h].x = fmaf(a, v.x, acc[h].x);
            acc[h].y = fmaf(a, v.y, acc[h].y);
            acc[h].z = fmaf(a, v.z, acc[h].z);
            acc[h].w = fmaf(a, v.w, acc[h].w);
        }
    }
#pragma unroll
    for (int h = 0; h < H; h++) *(float4*)&red[g][h][l * 4] = acc[h];
    __syncthreads();
    if (t < 32 * H) {
        int h = t >> 5, l2 = t & 31;
        float4 s = make_float4(0.f, 0.f, 0.f, 0.f);
#pragma unroll
        for (int gg = 0; gg < 8; gg++) {
            float4 r = *(const float4*)&red[gg][h][l2 * 4];
            s.x += r.x; s.y += r.y; s.z += r.z; s.w += r.w;
        }
        ((float4*)(S + ((size_t)h * Mm + m) * 128))[l2] = s;
    }
}

// T[n,:] = BN(xres[n,:]) + bias + sum_slots sum_h sd_a[slot,h] * eo[m_slot][h*128 + :]
// in-place: T == xres allowed (each thread reads then writes only its own elements)
template <int H>
__global__ __launch_bounds__(256) void node_agg(const int* __restrict__ offs,
                                                const float* __restrict__ sd,
                                                const float* __restrict__ eo,
                                                const float* __restrict__ bias,
                                                const float* __restrict__ AB,
                                                const float* __restrict__ xres,
                                                float* __restrict__ T) {
    int w = threadIdx.x >> 6, lane = threadIdx.x & 63;
    int n = blockIdx.x * 4 + w;
    if (n >= Nn) return;
    int base = offs[n];
    int deg = offs[n + 1] - base;
    float2 acc[H];
#pragma unroll
    for (int h = 0; h < H; h++) acc[h] = make_float2(0.f, 0.f);
    constexpr int SDW = (H == 2) ? 4 : 2;
    const float* sp = sd + (size_t)base * SDW;
    for (int c0 = 0; c0 < deg; c0 += 4) {
        int mi[4];
        float a0[4], a1[4];
#pragma unroll
        for (int j = 0; j < 4; j++) {
            int c = c0 + j;
            if (c < deg) {
                if (H == 2) {
                    float4 v = *(const float4*)(sp + (size_t)c * 4);
                    mi[j] = __float_as_int(v.x); a0[j] = v.y; a1[j] = v.z;
                } else {
                    float2 v = *(const float2*)(sp + (size_t)c * 2);
                    mi[j] = __float_as_int(v.x); a0[j] = v.y; a1[j] = 0.f;
                }
            } else {
                mi[j] = -1; a0[j] = 0.f; a1[j] = 0.f;
            }
        }
#pragma unroll
        for (int j = 0; j < 4; j++) {
            if (mi[j] < 0) continue;
            const float* er = eo + (size_t)mi[j] * (128 * H) + 2 * lane;
            float2 e0 = *(const float2*)er;
            acc[0].x = fmaf(a0[j], e0.x, acc[0].x);
            acc[0].y = fmaf(a0[j], e0.y, acc[0].y);
            if (H == 2) {
                float2 e1 = *(const float2*)(er + 128);
                acc[1].x = fmaf(a1[j], e1.x, acc[1].x);
                acc[1].y = fmaf(a1[j], e1.y, acc[1].y);
            }
        }
    }
    int col = 2 * lane;
    float2 xr = *(const float2*)(xres + (size_t)n * 128 + col);
    float2 A2 = *(const float2*)(AB + col);
    float2 B2 = *(const float2*)(AB + 128 + col);
    float b0 = xr.x * A2.x + B2.x;
    float b1 = xr.y * A2.y + B2.y;
    float r0 = b0 + bias[col] + acc[0].x + (H == 2 ? acc[1].x : 0.f);
    float r1 = b1 + bias[col + 1] + acc[0].y + (H == 2 ? acc[1].y : 0.f);
    *(float2*)(T + (size_t)n * 128 + col) = make_float2(r0, r1);
}

extern "C" void kernel_launch(void* const* d_in, const int* in_sizes, int n_in,
                              void* d_out, int out_size, void* d_ws, size_t ws_size,
                              hipStream_t stream) {
    const float* x = (const float*)d_in[0];
    const int* he_n = (const int*)d_in[1];
    const float* he_w = (const float*)d_in[3];
    const float* lin1_w = (const float*)d_in[4];
    const float* lin1_b = (const float*)d_in[5];
    const float* bn1_g = (const float*)d_in[6];
    const float* bn1_b = (const float*)d_in[7];
    const float* h1_w = (const float*)d_in[8];
    const float* h1_att = (const float*)d_in[9];
    const float* h1_b = (const float*)d_in[10];
    const float* bn2_g = (const float*)d_in[11];
    const float* bn2_b = (const float*)d_in[12];
    const float* h2_w = (const float*)d_in[13];
    const float* h2_att = (const float*)d_in[14];
    const float* h2_b = (const float*)d_in[15];
    const float* bn3_g = (const float*)d_in[16];
    const float* bn3_b = (const float*)d_in[17];
    const float* lin2_w = (const float*)d_in[18];
    const float* lin2_b = (const float*)d_in[19];
    const float* bn4_g = (const float*)d_in[20];
    const float* bn4_b = (const float*)d_in[21];
    float* out = (float*)d_out;

    char* ws = (char*)d_ws;
    size_t off = 0;
    auto alloc = [&](size_t bytes) -> char* {
        char* p = ws + off;
        off = (off + bytes + 255) & ~(size_t)255;
        return p;
    };
    // --- zeroed region (one memset) ---
    int* counts = (int*)alloc((size_t)Nn * 4);
    int* cursor = (int*)alloc((size_t)Nn * 4);
    double* stats = (double*)alloc((size_t)4 * 64 * 256 * 8);
    size_t zbytes = off;
    // --- rest ---
    int* offs = (int*)alloc((size_t)(Nn + 1) * 4);
    int* eid = (int*)alloc((size_t)Ee * 4);
    int* bsum = (int*)alloc(64 * 4);
    float* an = (float*)alloc((size_t)Nn * 2 * 4);
    float* pe = (float*)alloc((size_t)Nn * 2 * 4);
    float* ae = (float*)alloc((size_t)Mm * 2 * 4);
    float* aw = (float*)alloc((size_t)Ee * 2 * 4);
    float* sd = (float*)alloc((size_t)Ee * 4 * 4);
    float* S = (float*)alloc((size_t)2 * Mm * 128 * 4);
    float* eo = (float*)alloc((size_t)2 * Mm * 128 * 4);
    float* wn = (float*)alloc(2 * 128 * 4);
    float* we = (float*)alloc(2 * 128 * 4);
    float* AB = (float*)alloc(4 * 256 * 4);
    float* buf = (float*)alloc((size_t)Nn * 128 * 4);

    double* st0 = stats;
    double* st1 = stats + 64 * 256;
    double* st2 = stats + 2 * 64 * 256;
    double* st3 = stats + 3 * 64 * 256;
    float *AB1 = AB, *AB2 = AB + 256, *AB3 = AB + 512, *AB4 = AB + 768;

    hipMemsetAsync(d_ws, 0, zbytes, stream);

    constexpr int NB = (Nn + 1023) / 1024;  // 49
    // CSR by node
    count_edges<<<1250, 256, 0, stream>>>(he_n, counts);
    scan_block_sum<<<NB, 256, 0, stream>>>(counts, bsum);
    scan_top<<<1, 64, 0, stream>>>(bsum, NB, offs);
    scan_write<<<NB, 256, 0, stream>>>(counts, bsum, offs);
    fill_csr<<<1250, 256, 0, stream>>>(he_n, offs, cursor, eid);

    // stage 1: buf = lrelu(x@lin1_w + b) with fused bn1 stats
    gemmT<64, true, false, false, true><<<dim3((Nn + 63) / 64, 1), 256, 0, stream>>>(
        x, 0, lin1_w, 128, lin1_b, 1.f, nullptr, nullptr, st0, buf, 128, Nn);
    bn_finalize<<<1, 128, 0, stream>>>(st0, bn1_g, bn1_b, AB1);
    watt_kernel<2><<<1, 512, 0, stream>>>(h1_w, 256, h1_att, wn, we);
    bn_dots<2><<<12500, 256, 0, stream>>>(buf, AB1, wn, we, an, pe);

    // hgconv1 (H=2); BN1 applied inline from AB1
    ea_from_pe<2><<<Mm / 4, 256, 0, stream>>>(he_n, pe, ae);
    seg_softmax<2><<<(Nn + 31) / 32, 256, 0, stream>>>(offs, eid, an, ae, he_w, aw, sd);
    s_build<2><<<Mm, 256, 0, stream>>>(buf, AB1, he_n, aw, S);
    gemmT<32, false, false, false, false><<<dim3((Mm + 31) / 32, 2), 256, 0, stream>>>(
        S, (size_t)Mm * 128, h1_w, 256, nullptr, BINV, nullptr, nullptr, nullptr, eo, 256, Mm);
    node_agg<2><<<12500, 256, 0, stream>>>(offs, sd, eo, h1_b, AB1, buf, buf);

    // bn2
    col_stats<<<256, 256, 0, stream>>>(buf, st1);
    bn_finalize<<<1, 128, 0, stream>>>(st1, bn2_g, bn2_b, AB2);
    watt_kernel<1><<<1, 256, 0, stream>>>(h2_w, 128, h2_att, wn, we);
    bn_dots<1><<<12500, 256, 0, stream>>>(buf, AB2, wn, we, an, pe);

    // hgconv2 (H=1); BN2 applied inline from AB2
    ea_from_pe<1><<<Mm / 4, 256, 0, stream>>>(he_n, pe, ae);
    seg_softmax<1><<<(Nn + 31) / 32, 256, 0, stream>>>(offs, eid, an, ae, he_w, aw, sd);
    s_build<1><<<Mm, 256, 0, stream>>>(buf, AB2, he_n, aw, S);
    gemmT<32, false, false, false, false><<<dim3((Mm + 31) / 32, 1), 256, 0, stream>>>(
        S, 0, h2_w, 128, nullptr, BINV, nullptr, nullptr, nullptr, eo, 128, Mm);
    node_agg<1><<<12500, 256, 0, stream>>>(offs, sd, eo, h2_b, AB2, buf, buf);

    // bn3 stats; bn3-apply fused into lin2 GEMM prologue; lrelu+residual+bn4-stats in epilogue
    col_stats<<<256, 256, 0, stream>>>(buf, st2);
    bn_finalize<<<1, 128, 0, stream>>>(st2, bn3_g, bn3_b, AB3);
    gemmT<64, true, true, true, true><<<dim3((Nn + 63) / 64, 1), 256, 0, stream>>>(
        buf, 0, lin2_w, 128, lin2_b, 1.f, AB3, x, st3, buf, 128, Nn);
    bn_finalize<<<1, 128, 0, stream>>>(st3, bn4_g, bn4_b, AB4);
    bn_out<<<12500, 256, 0, stream>>>(buf, AB4, out);
}